// Round 13
// baseline (67.807 us; speedup 1.0000x reference)
//
#include <hip/hip_runtime.h>

// Problem constants (from reference)
#define SEQ_N   131072
#define ALPHA   4
#define DDIM    128

// Kernel-1 geometry: G1 * B1 * K1 == SEQ_N
#define G1      128
#define B1      128
#define K1      8

// Partial state layout (per chunk, product of unipotent lower-tri 4x4):
//   idx 0..5 : a,b,c,d,e,f   (P[1][0],P[2][1],P[3][2],P[2][0],P[3][1],P[3][0])
//   idx 6..9 : n0..n3        (character histogram, exact in fp32)

__global__ __launch_bounds__(B1) void wlts_partial_kernel(
        const int* __restrict__ seq,
        const float* __restrict__ sign_table,   // [3][4] row-major
        float* __restrict__ ws) {
    __shared__ float4 stab[ALPHA];          // per char c: (s1,s2,s3,0)
    __shared__ float red[2][10 * B1];       // ping-pong ordered tree reduce

    const int t = threadIdx.x;
    if (t < ALPHA) {
        stab[t] = make_float4(sign_table[0 * ALPHA + t],
                              sign_table[1 * ALPHA + t],
                              sign_table[2 * ALPHA + t], 0.f);
    }
    __syncthreads();

    // Sequential pass over this thread's contiguous chunk of K1 elements.
    const int gtid = blockIdx.x * B1 + t;
    const int4* p4 = reinterpret_cast<const int4*>(seq) + gtid * (K1 / 4);

    float a = 0.f, b = 0.f, c = 0.f, d = 0.f, e = 0.f, f = 0.f;
    float n0 = 0.f, n1 = 0.f, n2 = 0.f, n3 = 0.f;

    #pragma unroll
    for (int i = 0; i < K1 / 4; ++i) {
        const int4 v = p4[i];
        #pragma unroll
        for (int j = 0; j < 4; ++j) {
            const int ch = (j == 0) ? v.x : (j == 1) ? v.y : (j == 2) ? v.z : v.w;
            const float4 s = stab[ch];   // one ds_read_b128, 4 distinct banks
            // X = M(ch) applied AFTER accumulated Y=(a..f); use OLD a,b,d.
            f = fmaf(s.z, d, f);
            e = fmaf(s.z, b, e);
            d = fmaf(s.y, a, d);
            a += s.x;
            b += s.y;
            c += s.z;
            n0 += (ch == 0) ? 1.f : 0.f;
            n1 += (ch == 1) ? 1.f : 0.f;
            n2 += (ch == 2) ? 1.f : 0.f;
            n3 += (ch == 3) ? 1.f : 0.f;
        }
    }

    red[0][0 * B1 + t] = a;  red[0][1 * B1 + t] = b;
    red[0][2 * B1 + t] = c;  red[0][3 * B1 + t] = d;
    red[0][4 * B1 + t] = e;  red[0][5 * B1 + t] = f;
    red[0][6 * B1 + t] = n0; red[0][7 * B1 + t] = n1;
    red[0][8 * B1 + t] = n2; red[0][9 * B1 + t] = n3;

    // Ordered adjacent-pairwise tree reduce: new[t] = old[2t] (earlier, Y)
    // combined with old[2t+1] (later, X). Non-commutative — order matters.
    int buf = 0;
    for (int s = B1 / 2; s >= 1; s >>= 1) {
        __syncthreads();
        if (t < s) {
            const float* cur = red[buf];
            const int iY = 2 * t, iX = 2 * t + 1;
            const float aY = cur[0 * B1 + iY], bY = cur[1 * B1 + iY], cY = cur[2 * B1 + iY];
            const float dY = cur[3 * B1 + iY], eY = cur[4 * B1 + iY], fY = cur[5 * B1 + iY];
            const float aX = cur[0 * B1 + iX], bX = cur[1 * B1 + iX], cX = cur[2 * B1 + iX];
            const float dX = cur[3 * B1 + iX], eX = cur[4 * B1 + iX], fX = cur[5 * B1 + iX];
            float* nx = red[buf ^ 1];
            nx[0 * B1 + t] = aX + aY;
            nx[1 * B1 + t] = bX + bY;
            nx[2 * B1 + t] = cX + cY;
            nx[3 * B1 + t] = dY + fmaf(bX, aY, dX);
            nx[4 * B1 + t] = eY + fmaf(cX, bY, eX);
            nx[5 * B1 + t] = (fY + fX) + fmaf(eX, aY, cX * dY);
            nx[6 * B1 + t] = cur[6 * B1 + iY] + cur[6 * B1 + iX];
            nx[7 * B1 + t] = cur[7 * B1 + iY] + cur[7 * B1 + iX];
            nx[8 * B1 + t] = cur[8 * B1 + iY] + cur[8 * B1 + iX];
            nx[9 * B1 + t] = cur[9 * B1 + iY] + cur[9 * B1 + iX];
        }
        buf ^= 1;
    }
    __syncthreads();
    if (t < 10) ws[blockIdx.x * 10 + t] = red[buf][t * B1 + 0];
}

__global__ __launch_bounds__(DDIM) void wlts_final_kernel(
        const float* __restrict__ ws,           // [G1][10] block partials
        const float* __restrict__ gscale,       // scalar
        const float* __restrict__ char_scales,  // [4]
        const float* __restrict__ dim_weights,  // [128]
        const float* __restrict__ cpert,        // [4][128]
        float* __restrict__ out) {              // [128]
    __shared__ float red[2][10 * G1];
    const int t = threadIdx.x;   // 128 threads == G1 partials == DDIM outputs

    #pragma unroll
    for (int k = 0; k < 10; ++k) red[0][k * G1 + t] = ws[t * 10 + k];

    int buf = 0;
    for (int s = G1 / 2; s >= 1; s >>= 1) {
        __syncthreads();
        if (t < s) {
            const float* cur = red[buf];
            const int iY = 2 * t, iX = 2 * t + 1;
            const float aY = cur[0 * G1 + iY], bY = cur[1 * G1 + iY], cY = cur[2 * G1 + iY];
            const float dY = cur[3 * G1 + iY], eY = cur[4 * G1 + iY], fY = cur[5 * G1 + iY];
            const float aX = cur[0 * G1 + iX], bX = cur[1 * G1 + iX], cX = cur[2 * G1 + iX];
            const float dX = cur[3 * G1 + iX], eX = cur[4 * G1 + iX], fX = cur[5 * G1 + iX];
            float* nx = red[buf ^ 1];
            nx[0 * G1 + t] = aX + aY;
            nx[1 * G1 + t] = bX + bY;
            nx[2 * G1 + t] = cX + cY;
            nx[3 * G1 + t] = dY + fmaf(bX, aY, dX);
            nx[4 * G1 + t] = eY + fmaf(cX, bY, eX);
            nx[5 * G1 + t] = (fY + fX) + fmaf(eX, aY, cX * dY);
            nx[6 * G1 + t] = cur[6 * G1 + iY] + cur[6 * G1 + iX];
            nx[7 * G1 + t] = cur[7 * G1 + iY] + cur[7 * G1 + iX];
            nx[8 * G1 + t] = cur[8 * G1 + iY] + cur[8 * G1 + iX];
            nx[9 * G1 + t] = cur[9 * G1 + iY] + cur[9 * G1 + iX];
        }
        buf ^= 1;
    }
    __syncthreads();

    const float fT = red[buf][5 * G1 + 0];      // C_n
    const float c0 = red[buf][6 * G1 + 0];
    const float c1 = red[buf][7 * G1 + 0];
    const float c2 = red[buf][8 * G1 + 0];
    const float c3 = red[buf][9 * G1 + 0];

    const float inv_n = 1.0f / (float)SEQ_N;
    const float p0 = c0 * inv_n, p1 = c1 * inv_n, p2 = c2 * inv_n, p3 = c3 * inv_n;

    const float scaling = 0.9f + 0.2f * (p0 * char_scales[0] + p1 * char_scales[1] +
                                         p2 * char_scales[2] + p3 * char_scales[3]);
    const float baseline = fT * inv_n * (1.0f / (float)DDIM);   // C_n / (n*D), uniform over d
    const float pert = 0.1f * (p0 * cpert[0 * DDIM + t] + p1 * cpert[1 * DDIM + t] +
                               p2 * cpert[2 * DDIM + t] + p3 * cpert[3 * DDIM + t]);

    out[t] = baseline * gscale[0] * dim_weights[t] * scaling + pert;
}

extern "C" void kernel_launch(void* const* d_in, const int* in_sizes, int n_in,
                              void* d_out, int out_size, void* d_ws, size_t ws_size,
                              hipStream_t stream) {
    const int*   seq         = (const int*)d_in[0];
    // d_in[1] = hash_table: provably unused (roll is identity on uniform rows)
    const float* sign_table  = (const float*)d_in[2];
    const float* gscale      = (const float*)d_in[3];
    const float* char_scales = (const float*)d_in[4];
    const float* dim_weights = (const float*)d_in[5];
    const float* cpert       = (const float*)d_in[6];
    float* out = (float*)d_out;
    float* ws  = (float*)d_ws;

    hipLaunchKernelGGL(wlts_partial_kernel, dim3(G1), dim3(B1), 0, stream,
                       seq, sign_table, ws);
    hipLaunchKernelGGL(wlts_final_kernel, dim3(1), dim3(DDIM), 0, stream,
                       ws, gscale, char_scales, dim_weights, cpert, out);
}